// Round 10
// baseline (2379.215 us; speedup 1.0000x reference)
//
#include <hip/hip_runtime.h>
#include <hip/hip_bf16.h>

typedef __attribute__((ext_vector_type(8))) short short8;
typedef __attribute__((ext_vector_type(4))) float f32x4;

#define SEQ   256   // source length S
#define BB    16    // batch
#define EE    256   // embed dim
#define HH    256   // hidden
#define GG    1024  // 4*H
#define TT    128   // target_size
#define NWG   32    // persistent workgroups
#define KP    264   // LDS row stride in shorts
#define SLOT_S 8192 // shorts per h slot: 16 rows x 32 chunks x 16 (8 hi | 8 lo)
#define SENT  0xFF80FF80u   // packed bf16 [-inf|-inf]: unreachable for finite h
#define MAXTRY (1 << 20)

__device__ __forceinline__ float sigm(float x) { return 1.0f / (1.0f + __expf(-x)); }
__device__ __forceinline__ float tanh_f(float x) {
    float e = __expf(2.0f * x);
    return 1.0f - 2.0f / (e + 1.0f);
}
__device__ __forceinline__ void split2s(float v, short* hi, short* lo) {
    __hip_bfloat16 h = __float2bfloat16(v);
    __hip_bfloat16 l = __float2bfloat16(v - __bfloat162float(h));
    *hi = *(short*)&h; *lo = *(short*)&l;
}
__device__ __forceinline__ f32x4 MFMA(short8 a, short8 b, f32x4 c) {
    return __builtin_amdgcn_mfma_f32_16x16x32_bf16(a, b, c, 0, 0, 0);
}

// ---- LLC-direct accesses (sc0 sc1): bypass L1/L2, served at the coherence point ----
__device__ __forceinline__ short8 ld16s(const short* p) {
    short8 r;
    asm volatile("global_load_dwordx4 %0, %1, off sc0 sc1" : "=v"(r) : "v"(p));
    return r;   // valid only after vmwait()
}
__device__ __forceinline__ void st4s(int* p, int v) {
    asm volatile("global_store_dword %0, %1, off sc0 sc1" :: "v"(p), "v"(v) : "memory");
}
__device__ __forceinline__ void vmwait() {
    asm volatile("s_waitcnt vmcnt(0)" ::: "memory");
    __builtin_amdgcn_sched_barrier(0);
}
union U8 { short8 s; unsigned u[4]; };
__device__ __forceinline__ unsigned chk(short8 f) {
    U8 x; x.s = f;
    return (unsigned)((x.u[0] == SENT) | (x.u[1] == SENT) | (x.u[2] == SENT) | (x.u[3] == SENT));
}

// ---------------- utility kernels ----------------
__global__ void k_sent(unsigned* p) {   // fill slot region with sentinel, 16B/thread
    long i = ((long)blockIdx.x * 256 + threadIdx.x) * 4;
    p[i] = SENT; p[i + 1] = SENT; p[i + 2] = SENT; p[i + 3] = SENT;
}

// all four weight tensors in one launch: g = blockIdx>>11 selects tensor
__global__ void k_cvt4(const float* __restrict__ s0, const float* __restrict__ s1,
                       const float* __restrict__ s2, const float* __restrict__ s3,
                       char* __restrict__ ws) {
    int g = blockIdx.x >> 11;
    int i = (blockIdx.x & 2047) * 256 + threadIdx.x;       // 0..524287 (= 2*G*E)
    const float* s = (g == 0) ? s0 : (g == 1) ? s1 : (g == 2) ? s2 : s3;
    __hip_bfloat16* hi = (__hip_bfloat16*)(ws + ((size_t)2 * g) * (1u << 20));
    __hip_bfloat16* lo = (__hip_bfloat16*)(ws + ((size_t)2 * g + 1) * (1u << 20));
    short a, b; split2s(s[i], &a, &b);
    hi[i] = *(__hip_bfloat16*)&a; lo[i] = *(__hip_bfloat16*)&b;
}

__global__ void k_embed(const int* __restrict__ src, const float* __restrict__ tab,
                        __hip_bfloat16* __restrict__ xhi, __hip_bfloat16* __restrict__ xlo) {
    int r = blockIdx.x;
    int j = threadIdx.x;
    long idx = src[r];
    short a, b; split2s(tab[idx * EE + j], &a, &b);
    xhi[(long)r * EE + j] = *(__hip_bfloat16*)&a;
    xlo[(long)r * EE + j] = *(__hip_bfloat16*)&b;
}

// ------------- input-side GEMM: gates0T[row][j][q] = X @ Wih0^T + bih0 + bhh0 -------------
__global__ void __launch_bounds__(256) k_gemm_in(
        const __hip_bfloat16* __restrict__ Xhi, const __hip_bfloat16* __restrict__ Xlo,
        const __hip_bfloat16* __restrict__ Whi, const __hip_bfloat16* __restrict__ Wlo,
        const float* __restrict__ bih, const float* __restrict__ bhh,
        float* __restrict__ gates) {
    int lane = threadIdx.x & 63, w = threadIdx.x >> 6;
    int m0 = (blockIdx.x >> 4) * 16;
    int n0 = ((blockIdx.x & 15) * 4 + w) * 16;
    int cc = lane & 15, g = lane >> 4;
    int koff = g * 8;
    const short* xh = (const short*)Xhi + (long)(m0 + cc) * EE + koff;
    const short* xl = (const short*)Xlo + (long)(m0 + cc) * EE + koff;
    const short* wh = (const short*)Whi + (long)(n0 + cc) * EE + koff;
    const short* wl = (const short*)Wlo + (long)(n0 + cc) * EE + koff;
    f32x4 acc1 = {0.f, 0.f, 0.f, 0.f}, acc2 = {0.f, 0.f, 0.f, 0.f};
#pragma unroll
    for (int k = 0; k < EE; k += 32) {
        short8 ah = *(const short8*)(xh + k), al = *(const short8*)(xl + k);
        short8 bh = *(const short8*)(wh + k), bl = *(const short8*)(wl + k);
        acc1 = MFMA(ah, bh, acc1);
        acc2 = MFMA(ah, bl, acc2);
        acc2 = MFMA(al, bh, acc2);
    }
    f32x4 acc = acc1 + acc2;
    int ncol = n0 + cc;
    float bias = bih[ncol] + bhh[ncol];
    int jj = ncol & 255, qq = ncol >> 8;
    int mrow = m0 + g * 4;
#pragma unroll
    for (int r = 0; r < 4; ++r)
        gates[(long)(mrow + r) * GG + jj * 4 + qq] = acc[r] + bias;   // transposed
}

// ---- gather one 32-row weight slice into LDS ----
__device__ __forceinline__ void load_wslice(const short* __restrict__ Wg, int j0,
                                            short* __restrict__ Wl) {
    int tid = threadIdx.x;
    int lr = tid >> 3;
    int q = lr >> 3, jl = lr & 7;
    const short* src = Wg + (long)(q * 256 + j0 + jl) * 256;
    short* dst = Wl + lr * KP;
#pragma unroll
    for (int s = 0; s < 4; ++s) {
        int c = (tid & 7) * 8 + s * 64;
        *(short8*)(dst + c) = *(const short8*)(src + c);
    }
}

// slot layout: [row 0..15][chunk 0..31][8 hi shorts | 8 lo shorts]; chunk c = j/8

// ---------------- encoder: dataflow wavefront, no barriers ----------------
__global__ void __launch_bounds__(256, 1) k_enc_coop(
        const float* __restrict__ gates0,                 // [4096][256][4] transposed
        const short* __restrict__ Whh0h, const short* __restrict__ Whh0l,
        const short* __restrict__ Wih1h, const short* __restrict__ Wih1l,
        const short* __restrict__ Whh1h, const short* __restrict__ Whh1l,
        const float* __restrict__ bih1, const float* __restrict__ bhh1,
        const float* __restrict__ h0p, const float* __restrict__ c0p,
        short* __restrict__ H0, short* __restrict__ H1,    // [257][SLOT_S]
        float* __restrict__ hfin) {
    __shared__ short Wl[6][32 * KP];
    __shared__ float gacc[2][8][16][17];

    int tid = threadIdx.x, bid = blockIdx.x;
    int j0 = bid * 8;
    load_wslice(Whh0h, j0, Wl[0]); load_wslice(Whh0l, j0, Wl[1]);
    load_wslice(Wih1h, j0, Wl[2]); load_wslice(Wih1l, j0, Wl[3]);
    load_wslice(Whh1h, j0, Wl[4]); load_wslice(Whh1l, j0, Wl[5]);

    int bb = (tid & 127) >> 3, jl = tid & 7, j = j0 + jl, lay = tid >> 7;
    float creg = c0p[lay * 4096 + bb * 256 + j];
    float bs[4] = {0.f, 0.f, 0.f, 0.f};
    if (lay) {
#pragma unroll
        for (int q = 0; q < 4; ++q) bs[q] = bih1[q * 256 + j] + bhh1[q * 256 + j];
    }
    f32x4 gnew = {0.f, 0.f, 0.f, 0.f};
    if (!lay) {   // initial prefetch for t=0 (plain load, completes before loop)
        gnew = *(const f32x4*)(gates0 + ((long)bb * 256 + j) * 4);
    }
    {   // init: state slot 0
        float hv = h0p[lay * 4096 + bb * 256 + j];
        short sh, sl; split2s(hv, &sh, &sl);
        int mh = (unsigned short)sh, ml = (unsigned short)sl;
        int nh = __shfl_down(mh, 1), nl = __shfl_down(ml, 1);
        int* dst = (int*)(lay ? H1 : H0);
        if (!(jl & 1)) {
            int idx = bb * 256 + bid * 8 + (jl >> 1);
            st4s(dst + idx, mh | (nh << 16));
            st4s(dst + idx + 4, ml | (nl << 16));
        }
    }

    int lane = tid & 63, w = tid >> 6, cc = lane & 15, g4 = lane >> 4;
    int tw = w & 1, kb = (w >> 1) * 128;
    int abase = cc * 512 + kb * 2 + g4 * 16;       // shorts into a slot
    int wr = (tw * 16 + cc) * KP + kb + (g4 * 8);

    for (int i = 0; i <= SEQ; ++i) {
        bool actL0 = (i < SEQ), actL1 = (i >= 1);
        int par = i & 1;

        // ---- dataflow poll: h0 slot i (L0 h-state AND L1 x) and h1 slot i-1 ----
        short8 f0h[4], f0l[4], f1h[4], f1l[4];
        const short* b0 = H0 + (long)i * SLOT_S + abase;
        const short* b1 = H1 + (long)(i - 1) * SLOT_S + abase;
        int tries = 0;
        while (true) {
#pragma unroll
            for (int ki = 0; ki < 4; ++ki) {
                f0h[ki] = ld16s(b0 + ki * 64);
                f0l[ki] = ld16s(b0 + ki * 64 + 8);
            }
            if (actL1) {
#pragma unroll
                for (int ki = 0; ki < 4; ++ki) {
                    f1h[ki] = ld16s(b1 + ki * 64);
                    f1l[ki] = ld16s(b1 + ki * 64 + 8);
                }
            }
            vmwait();
            unsigned bad = 0;
#pragma unroll
            for (int ki = 0; ki < 4; ++ki) bad |= chk(f0h[ki]) | chk(f0l[ki]);
            if (actL1) {
#pragma unroll
                for (int ki = 0; ki < 4; ++ki) bad |= chk(f1h[ki]) | chk(f1l[ki]);
            }
            if (!__any((int)bad) || ++tries > MAXTRY) break;
        }

        // ---- rotate gates prefetch: consume last iteration's value, then issue
        //      next step's as a PLAIN load (compiler-tracked waits; in-order vmcnt
        //      retirement keeps its waits correct despite our asm poll loads) ----
        float gpre[4] = {0.f, 0.f, 0.f, 0.f};
        if (!lay) {
#pragma unroll
            for (int q = 0; q < 4; ++q) gpre[q] = gnew[q];
            if (i + 1 < SEQ)
                gnew = *(const f32x4*)(gates0 + ((long)((i + 1) * BB + bb) * 256 + j) * 4);
        }

        f32x4 z = {0.f, 0.f, 0.f, 0.f};
        f32x4 s0 = z, s1 = z;
        if (actL0) {
            f32x4 a1 = z, a2 = z;
#pragma unroll
            for (int ki = 0; ki < 4; ++ki) {
                short8 wh  = *(const short8*)(Wl[0] + wr + ki * 32);
                short8 wl2 = *(const short8*)(Wl[1] + wr + ki * 32);
                a1 = MFMA(f0h[ki], wh, a1);
                a2 = MFMA(f0h[ki], wl2, a2);
                a2 = MFMA(f0l[ki], wh, a2);
            }
            s0 = a1 + a2;
        }
        if (actL1) {
            f32x4 a1 = z, a2 = z;
#pragma unroll
            for (int ki = 0; ki < 4; ++ki) {
                a1 = MFMA(f0h[ki], *(const short8*)(Wl[2] + wr + ki * 32), a1);
                a2 = MFMA(f0h[ki], *(const short8*)(Wl[3] + wr + ki * 32), a2);
                a2 = MFMA(f0l[ki], *(const short8*)(Wl[2] + wr + ki * 32), a2);
                a1 = MFMA(f1h[ki], *(const short8*)(Wl[4] + wr + ki * 32), a1);
                a2 = MFMA(f1h[ki], *(const short8*)(Wl[5] + wr + ki * 32), a2);
                a2 = MFMA(f1l[ki], *(const short8*)(Wl[4] + wr + ki * 32), a2);
            }
            s1 = a1 + a2;
        }
#pragma unroll
        for (int r = 0; r < 4; ++r) {
            gacc[par][w][g4 * 4 + r][cc] = s0[r];
            gacc[par][4 + w][g4 * 4 + r][cc] = s1[r];
        }
        __syncthreads();

        bool act = lay ? actL1 : actL0;
        if (act) {
            int t = lay ? (i - 1) : i;
            float gv[4];
#pragma unroll
            for (int q = 0; q < 4; ++q) {
                int lr = q * 8 + jl, tl = lr >> 4, c = lr & 15;
                gv[q] = lay ? (gacc[par][4 + tl][bb][c] + gacc[par][6 + tl][bb][c] + bs[q])
                            : (gacc[par][tl][bb][c] + gacc[par][2 + tl][bb][c] + gpre[q]);
            }
            float c = sigm(gv[1]) * creg + sigm(gv[0]) * tanh_f(gv[2]);
            creg = c;
            float h = sigm(gv[3]) * tanh_f(c);
            short sh, sl; split2s(h, &sh, &sl);
            int mh = (unsigned short)sh, ml = (unsigned short)sl;
            int nh = __shfl_down(mh, 1), nl = __shfl_down(ml, 1);
            int* dst = (int*)(lay ? (H1 + (long)i * SLOT_S) : (H0 + (long)(i + 1) * SLOT_S));
            if (!(jl & 1)) {
                int idx = bb * 256 + bid * 8 + (jl >> 1);
                st4s(dst + idx, mh | (nh << 16));
                st4s(dst + idx + 4, ml | (nl << 16));
            }
            if (t == SEQ - 1) hfin[lay * 4096 + bb * 256 + j] = h;
        }
    }
}

// ---------------- decoder: dataflow, 2 phases/step, register h-handoff ----------------
__global__ void __launch_bounds__(256, 1) k_dec_coop(
        const short* __restrict__ Wihh, const short* __restrict__ Wihl,
        const short* __restrict__ Whhh, const short* __restrict__ Whhl,
        const float* __restrict__ dbih, const float* __restrict__ dbhh,
        const float* __restrict__ tef, const float* __restrict__ hfin,
        short* __restrict__ H0, short* __restrict__ H1,    // [128][SLOT_S]
        short* __restrict__ TE,                            // [SLOT_S]
        float* __restrict__ preds) {
    __shared__ short Wl[8][32 * KP];
    __shared__ float gacc[2][4][16][17];
    const int WN = GG * EE;

    int tid = threadIdx.x, bid = blockIdx.x;
    int j0 = bid * 8;
    load_wslice(Wihh, j0, Wl[0]);      load_wslice(Wihl, j0, Wl[1]);
    load_wslice(Whhh, j0, Wl[2]);      load_wslice(Whhl, j0, Wl[3]);
    load_wslice(Wihh + WN, j0, Wl[4]); load_wslice(Wihl + WN, j0, Wl[5]);
    load_wslice(Whhh + WN, j0, Wl[6]); load_wslice(Whhl + WN, j0, Wl[7]);

    int bb = (tid & 127) >> 3, jl = tid & 7, j = j0 + jl;
    float c0r = 0.f, c1r = 0.f;
    float bs0[4] = {0,0,0,0}, bs1[4] = {0,0,0,0};
    if (tid < 128) {
        float h0v = hfin[bb * 256 + j], h1v = hfin[4096 + bb * 256 + j];
        c0r = h0v; c1r = h1v;                      // source bug: c := h
        preds[bb * 256 + j] = 0.0f;                // predictions[0] = 0
        int idx = bb * 256 + bid * 8 + (jl >> 1);
        short sh, sl;
        split2s(tef[j], &sh, &sl);
        {
            int mh = (unsigned short)sh, ml = (unsigned short)sl;
            int nh = __shfl_down(mh, 1), nl = __shfl_down(ml, 1);
            if (!(jl & 1)) { st4s((int*)TE + idx, mh | (nh << 16));
                             st4s((int*)TE + idx + 4, ml | (nl << 16)); }
        }
        split2s(h0v, &sh, &sl);
        {
            int mh = (unsigned short)sh, ml = (unsigned short)sl;
            int nh = __shfl_down(mh, 1), nl = __shfl_down(ml, 1);
            if (!(jl & 1)) { st4s((int*)H0 + idx, mh | (nh << 16));
                             st4s((int*)H0 + idx + 4, ml | (nl << 16)); }
        }
        split2s(h1v, &sh, &sl);
        {
            int mh = (unsigned short)sh, ml = (unsigned short)sl;
            int nh = __shfl_down(mh, 1), nl = __shfl_down(ml, 1);
            if (!(jl & 1)) { st4s((int*)H1 + idx, mh | (nh << 16));
                             st4s((int*)H1 + idx + 4, ml | (nl << 16)); }
        }
#pragma unroll
        for (int q = 0; q < 4; ++q) {
            bs0[q] = dbih[q*256+j] + dbhh[q*256+j];
            bs1[q] = dbih[GG + q*256+j] + dbhh[GG + q*256+j];
        }
    }

    int lane = tid & 63, w = tid >> 6, cc = lane & 15, g4 = lane >> 4;
    int tw = w & 1, kb = (w >> 1) * 128;
    int abase = cc * 512 + kb * 2 + g4 * 16;
    int wr = (tw * 16 + cc) * KP + kb + (g4 * 8);

    short8 xAh[4], xAl[4], xBh[4], xBl[4], h1ih[4], h1il[4];

    // preload: xB := H0[0], h1i := H1[0] (dataflow poll)
    {
        const short* p0 = H0 + abase;
        const short* p1 = H1 + abase;
        int tries = 0;
        while (true) {
#pragma unroll
            for (int ki = 0; ki < 4; ++ki) {
                xBh[ki] = ld16s(p0 + ki * 64); xBl[ki] = ld16s(p0 + ki * 64 + 8);
                h1ih[ki] = ld16s(p1 + ki * 64); h1il[ki] = ld16s(p1 + ki * 64 + 8);
            }
            vmwait();
            unsigned bad = 0;
#pragma unroll
            for (int ki = 0; ki < 4; ++ki)
                bad |= chk(xBh[ki]) | chk(xBl[ki]) | chk(h1ih[ki]) | chk(h1il[ki]);
            if (!__any((int)bad) || ++tries > MAXTRY) break;
        }
    }

    for (int t = 0; t < TT - 1; ++t) {
        // ---- phase A: layer 0 : x = (t? H1[t] : TE) polled, h = xB regs ----
        {
            const short* px = (t ? H1 + (long)t * SLOT_S : TE) + abase;
            int tries = 0;
            while (true) {
#pragma unroll
                for (int ki = 0; ki < 4; ++ki) {
                    xAh[ki] = ld16s(px + ki * 64); xAl[ki] = ld16s(px + ki * 64 + 8);
                }
                vmwait();
                unsigned bad = 0;
#pragma unroll
                for (int ki = 0; ki < 4; ++ki) bad |= chk(xAh[ki]) | chk(xAl[ki]);
                if (!__any((int)bad) || ++tries > MAXTRY) break;
            }
            f32x4 a1 = {0.f,0.f,0.f,0.f}, a2 = {0.f,0.f,0.f,0.f};
#pragma unroll
            for (int ki = 0; ki < 4; ++ki) {
                a1 = MFMA(xAh[ki], *(const short8*)(Wl[0] + wr + ki * 32), a1);
                a2 = MFMA(xAh[ki], *(const short8*)(Wl[1] + wr + ki * 32), a2);
                a2 = MFMA(xAl[ki], *(const short8*)(Wl[0] + wr + ki * 32), a2);
                a1 = MFMA(xBh[ki], *(const short8*)(Wl[2] + wr + ki * 32), a1);
                a2 = MFMA(xBh[ki], *(const short8*)(Wl[3] + wr + ki * 32), a2);
                a2 = MFMA(xBl[ki], *(const short8*)(Wl[2] + wr + ki * 32), a2);
            }
            f32x4 accs = a1 + a2;
#pragma unroll
            for (int r = 0; r < 4; ++r) gacc[0][w][g4 * 4 + r][cc] = accs[r];
        }
        __syncthreads();
        if (tid < 128) {
            float gv[4];
#pragma unroll
            for (int q = 0; q < 4; ++q) {
                int lr = q * 8 + jl;
                gv[q] = gacc[0][lr >> 4][bb][lr & 15] + gacc[0][2 + (lr >> 4)][bb][lr & 15] + bs0[q];
            }
            float c = sigm(gv[1]) * c0r + sigm(gv[0]) * tanh_f(gv[2]);
            c0r = c;
            float h = sigm(gv[3]) * tanh_f(c);
            short sh, sl; split2s(h, &sh, &sl);
            int mh = (unsigned short)sh, ml = (unsigned short)sl;
            int nh = __shfl_down(mh, 1), nl = __shfl_down(ml, 1);
            if (!(jl & 1)) {
                int idx = bb * 256 + bid * 8 + (jl >> 1);
                int* dst = (int*)(H0 + (long)(t + 1) * SLOT_S);
                st4s(dst + idx, mh | (nh << 16));
                st4s(dst + idx + 4, ml | (nl << 16));
            }
        }
        // ---- phase B: layer 1 : x = H0[t+1] polled, h = (t? xA : h1i) regs ----
        {
            const short* px = H0 + (long)(t + 1) * SLOT_S + abase;
            int tries = 0;
            while (true) {
#pragma unroll
                for (int ki = 0; ki < 4; ++ki) {
                    xBh[ki] = ld16s(px + ki * 64); xBl[ki] = ld16s(px + ki * 64 + 8);
                }
                vmwait();
                unsigned bad = 0;
#pragma unroll
                for (int ki = 0; ki < 4; ++ki) bad |= chk(xBh[ki]) | chk(xBl[ki]);
                if (!__any((int)bad) || ++tries > MAXTRY) break;
            }
            f32x4 a1 = {0.f,0.f,0.f,0.f}, a2 = {0.f,0.f,0.f,0.f};
#pragma unroll
            for (int ki = 0; ki < 4; ++ki) {
                short8 hh = t ? xAh[ki] : h1ih[ki];
                short8 hl = t ? xAl[ki] : h1il[ki];
                a1 = MFMA(xBh[ki], *(const short8*)(Wl[4] + wr + ki * 32), a1);
                a2 = MFMA(xBh[ki], *(const short8*)(Wl[5] + wr + ki * 32), a2);
                a2 = MFMA(xBl[ki], *(const short8*)(Wl[4] + wr + ki * 32), a2);
                a1 = MFMA(hh, *(const short8*)(Wl[6] + wr + ki * 32), a1);
                a2 = MFMA(hh, *(const short8*)(Wl[7] + wr + ki * 32), a2);
                a2 = MFMA(hl, *(const short8*)(Wl[6] + wr + ki * 32), a2);
            }
            f32x4 accs = a1 + a2;
#pragma unroll
            for (int r = 0; r < 4; ++r) gacc[1][w][g4 * 4 + r][cc] = accs[r];
        }
        __syncthreads();
        if (tid < 128) {
            float gv[4];
#pragma unroll
            for (int q = 0; q < 4; ++q) {
                int lr = q * 8 + jl;
                gv[q] = gacc[1][lr >> 4][bb][lr & 15] + gacc[1][2 + (lr >> 4)][bb][lr & 15] + bs1[q];
            }
            float c = sigm(gv[1]) * c1r + sigm(gv[0]) * tanh_f(gv[2]);
            c1r = c;
            float h = sigm(gv[3]) * tanh_f(c);
            short sh, sl; split2s(h, &sh, &sl);
            int mh = (unsigned short)sh, ml = (unsigned short)sl;
            int nh = __shfl_down(mh, 1), nl = __shfl_down(ml, 1);
            if (!(jl & 1)) {
                int idx = bb * 256 + bid * 8 + (jl >> 1);
                int* dst = (int*)(H1 + (long)(t + 1) * SLOT_S);
                st4s(dst + idx, mh | (nh << 16));
                st4s(dst + idx + 4, ml | (nl << 16));
            }
            preds[((long)(t + 1) * BB + bb) * HH + j] = h;
        }
    }
}

// ---------------- host launch ----------------
extern "C" void kernel_launch(void* const* d_in, const int* in_sizes, int n_in,
                              void* d_out, int out_size, void* d_ws, size_t ws_size,
                              hipStream_t stream) {
    const int*   src   = (const int*)  d_in[0];
    const float* te    = (const float*)d_in[2];
    const float* h0    = (const float*)d_in[3];
    const float* c0    = (const float*)d_in[4];
    const float* table = (const float*)d_in[5];
    const float* eWih  = (const float*)d_in[6];
    const float* eWhh  = (const float*)d_in[7];
    const float* ebih  = (const float*)d_in[8];
    const float* ebhh  = (const float*)d_in[9];
    const float* dWih  = (const float*)d_in[10];
    const float* dWhh  = (const float*)d_in[11];
    const float* dbih  = (const float*)d_in[12];
    const float* dbhh  = (const float*)d_in[13];
    float* preds = (float*)d_out;

    const int WN = GG * EE;
    const size_t MB = 1u << 20;
    char* ws = (char*)d_ws;
    short* eWih_hi = (short*)(ws + 0 * MB);
    short* eWih_lo = (short*)(ws + 1 * MB);
    short* eWhh_hi = (short*)(ws + 2 * MB);
    short* eWhh_lo = (short*)(ws + 3 * MB);
    short* dWih_hi = (short*)(ws + 4 * MB);
    short* dWih_lo = (short*)(ws + 5 * MB);
    short* dWhh_hi = (short*)(ws + 6 * MB);
    short* dWhh_lo = (short*)(ws + 7 * MB);
    short* Xa_hi   = (short*)(ws + 8 * MB);
    short* Xa_lo   = (short*)(ws + 10 * MB);
    float* hfin    = (float*)(ws + 12 * MB);
    short* slots   = (short*)(ws + 13 * MB);
    short* SLe0 = slots;
    short* SLe1 = SLe0 + (long)257 * SLOT_S;
    short* SLd0 = SLe1 + (long)257 * SLOT_S;
    short* SLd1 = SLd0 + (long)128 * SLOT_S;
    short* SLte = SLd1 + (long)128 * SLOT_S;
    float* gates0 = (float*)(ws + 26 * MB);    // [4096][256][4] transposed

    // sentinel-fill all 771 slots (16KB each)
    k_sent<<<3084, 256, 0, stream>>>((unsigned*)slots);

    // all four weight tensors in one launch
    k_cvt4<<<8192, 256, 0, stream>>>(eWih, eWhh, dWih, dWhh, ws);

    k_embed<<<4096, 256, 0, stream>>>(src, table, (__hip_bfloat16*)Xa_hi, (__hip_bfloat16*)Xa_lo);
    k_gemm_in<<<4096, 256, 0, stream>>>((__hip_bfloat16*)Xa_hi, (__hip_bfloat16*)Xa_lo,
                                        (__hip_bfloat16*)eWih_hi, (__hip_bfloat16*)eWih_lo,
                                        ebih, ebhh, gates0);
    k_enc_coop<<<NWG, 256, 0, stream>>>(gates0, eWhh_hi, eWhh_lo,
                                        eWih_hi + WN, eWih_lo + WN, eWhh_hi + WN, eWhh_lo + WN,
                                        ebih + GG, ebhh + GG, h0, c0,
                                        SLe0, SLe1, hfin);

    k_dec_coop<<<NWG, 256, 0, stream>>>(dWih_hi, dWih_lo, dWhh_hi, dWhh_lo,
                                        dbih, dbhh, te, hfin,
                                        SLd0, SLd1, SLte, preds);
    (void)in_sizes; (void)n_in; (void)out_size; (void)ws_size;
}

// Round 11
// 2368.918 us; speedup vs baseline: 1.0043x; 1.0043x over previous
//
#include <hip/hip_runtime.h>
#include <hip/hip_bf16.h>

typedef __attribute__((ext_vector_type(8))) short short8;
typedef __attribute__((ext_vector_type(4))) float f32x4;

#define SEQ   256   // source length S
#define BB    16    // batch
#define EE    256   // embed dim
#define HH    256   // hidden
#define GG    1024  // 4*H
#define TT    128   // target_size
#define NWG   32    // persistent workgroups
#define KP    264   // LDS row stride in shorts
#define SLOT_S 8192 // shorts per h slot: 16 rows x 32 chunks x 16 (8 hi | 8 lo)
#define SENT  0xFF80FF80u   // packed bf16 [-inf|-inf]: unreachable for finite h
#define MAXTRY (1 << 20)

__device__ __forceinline__ float sigm(float x) { return 1.0f / (1.0f + __expf(-x)); }
__device__ __forceinline__ float tanh_f(float x) {
    float e = __expf(2.0f * x);
    return 1.0f - 2.0f / (e + 1.0f);
}
__device__ __forceinline__ void split2s(float v, short* hi, short* lo) {
    __hip_bfloat16 h = __float2bfloat16(v);
    __hip_bfloat16 l = __float2bfloat16(v - __bfloat162float(h));
    *hi = *(short*)&h; *lo = *(short*)&l;
}
__device__ __forceinline__ f32x4 MFMA(short8 a, short8 b, f32x4 c) {
    return __builtin_amdgcn_mfma_f32_16x16x32_bf16(a, b, c, 0, 0, 0);
}

// ---- LLC-direct accesses (sc0 sc1): bypass L1/L2, served at the coherence point ----
__device__ __forceinline__ short8 ld16s(const short* p) {
    short8 r;
    asm volatile("global_load_dwordx4 %0, %1, off sc0 sc1" : "=v"(r) : "v"(p));
    return r;   // valid only after vmwait()
}
__device__ __forceinline__ void st4s(int* p, int v) {
    asm volatile("global_store_dword %0, %1, off sc0 sc1" :: "v"(p), "v"(v) : "memory");
}
__device__ __forceinline__ void vmwait() {
    asm volatile("s_waitcnt vmcnt(0)" ::: "memory");
    __builtin_amdgcn_sched_barrier(0);
}
// LDS-only block barrier: does NOT drain vmcnt — in-flight global stores/loads
// (h-state st4s, gates0 prefetch) cross freely; gacc LDS traffic is covered.
__device__ __forceinline__ void sync_lds() {
    __builtin_amdgcn_sched_barrier(0);
    asm volatile("s_waitcnt lgkmcnt(0)" ::: "memory");
    __builtin_amdgcn_s_barrier();
    __builtin_amdgcn_sched_barrier(0);
}
union U8 { short8 s; unsigned u[4]; };
__device__ __forceinline__ unsigned chk(short8 f) {
    U8 x; x.s = f;
    return (unsigned)((x.u[0] == SENT) | (x.u[1] == SENT) | (x.u[2] == SENT) | (x.u[3] == SENT));
}

// ---------------- utility kernels ----------------
__global__ void k_sent(unsigned* p) {   // fill slot region with sentinel, 16B/thread
    long i = ((long)blockIdx.x * 256 + threadIdx.x) * 4;
    p[i] = SENT; p[i + 1] = SENT; p[i + 2] = SENT; p[i + 3] = SENT;
}

// all four weight tensors in one launch: g = blockIdx>>11 selects tensor
__global__ void k_cvt4(const float* __restrict__ s0, const float* __restrict__ s1,
                       const float* __restrict__ s2, const float* __restrict__ s3,
                       char* __restrict__ ws) {
    int g = blockIdx.x >> 11;
    int i = (blockIdx.x & 2047) * 256 + threadIdx.x;       // 0..524287 (= 2*G*E)
    const float* s = (g == 0) ? s0 : (g == 1) ? s1 : (g == 2) ? s2 : s3;
    __hip_bfloat16* hi = (__hip_bfloat16*)(ws + ((size_t)2 * g) * (1u << 20));
    __hip_bfloat16* lo = (__hip_bfloat16*)(ws + ((size_t)2 * g + 1) * (1u << 20));
    short a, b; split2s(s[i], &a, &b);
    hi[i] = *(__hip_bfloat16*)&a; lo[i] = *(__hip_bfloat16*)&b;
}

__global__ void k_embed(const int* __restrict__ src, const float* __restrict__ tab,
                        __hip_bfloat16* __restrict__ xhi, __hip_bfloat16* __restrict__ xlo) {
    int r = blockIdx.x;
    int j = threadIdx.x;
    long idx = src[r];
    short a, b; split2s(tab[idx * EE + j], &a, &b);
    xhi[(long)r * EE + j] = *(__hip_bfloat16*)&a;
    xlo[(long)r * EE + j] = *(__hip_bfloat16*)&b;
}

// ------------- input-side GEMM: gates0T[row][j][q] = X @ Wih0^T + bih0 + bhh0 -------------
__global__ void __launch_bounds__(256) k_gemm_in(
        const __hip_bfloat16* __restrict__ Xhi, const __hip_bfloat16* __restrict__ Xlo,
        const __hip_bfloat16* __restrict__ Whi, const __hip_bfloat16* __restrict__ Wlo,
        const float* __restrict__ bih, const float* __restrict__ bhh,
        float* __restrict__ gates) {
    int lane = threadIdx.x & 63, w = threadIdx.x >> 6;
    int m0 = (blockIdx.x >> 4) * 16;
    int n0 = ((blockIdx.x & 15) * 4 + w) * 16;
    int cc = lane & 15, g = lane >> 4;
    int koff = g * 8;
    const short* xh = (const short*)Xhi + (long)(m0 + cc) * EE + koff;
    const short* xl = (const short*)Xlo + (long)(m0 + cc) * EE + koff;
    const short* wh = (const short*)Whi + (long)(n0 + cc) * EE + koff;
    const short* wl = (const short*)Wlo + (long)(n0 + cc) * EE + koff;
    f32x4 acc1 = {0.f, 0.f, 0.f, 0.f}, acc2 = {0.f, 0.f, 0.f, 0.f};
#pragma unroll
    for (int k = 0; k < EE; k += 32) {
        short8 ah = *(const short8*)(xh + k), al = *(const short8*)(xl + k);
        short8 bh = *(const short8*)(wh + k), bl = *(const short8*)(wl + k);
        acc1 = MFMA(ah, bh, acc1);
        acc2 = MFMA(ah, bl, acc2);
        acc2 = MFMA(al, bh, acc2);
    }
    f32x4 acc = acc1 + acc2;
    int ncol = n0 + cc;
    float bias = bih[ncol] + bhh[ncol];
    int jj = ncol & 255, qq = ncol >> 8;
    int mrow = m0 + g * 4;
#pragma unroll
    for (int r = 0; r < 4; ++r)
        gates[(long)(mrow + r) * GG + jj * 4 + qq] = acc[r] + bias;   // transposed
}

// ---- gather one 32-row weight slice into LDS ----
__device__ __forceinline__ void load_wslice(const short* __restrict__ Wg, int j0,
                                            short* __restrict__ Wl) {
    int tid = threadIdx.x;
    int lr = tid >> 3;
    int q = lr >> 3, jl = lr & 7;
    const short* src = Wg + (long)(q * 256 + j0 + jl) * 256;
    short* dst = Wl + lr * KP;
#pragma unroll
    for (int s = 0; s < 4; ++s) {
        int c = (tid & 7) * 8 + s * 64;
        *(short8*)(dst + c) = *(const short8*)(src + c);
    }
}

// slot layout: [row 0..15][chunk 0..31][8 hi shorts | 8 lo shorts]; chunk c = j/8

// ---------------- encoder: dataflow wavefront, no full barriers ----------------
__global__ void __launch_bounds__(256, 1) k_enc_coop(
        const float* __restrict__ gates0,                 // [4096][256][4] transposed
        const short* __restrict__ Whh0h, const short* __restrict__ Whh0l,
        const short* __restrict__ Wih1h, const short* __restrict__ Wih1l,
        const short* __restrict__ Whh1h, const short* __restrict__ Whh1l,
        const float* __restrict__ bih1, const float* __restrict__ bhh1,
        const float* __restrict__ h0p, const float* __restrict__ c0p,
        short* __restrict__ H0, short* __restrict__ H1,    // [257][SLOT_S]
        float* __restrict__ hfin) {
    __shared__ short Wl[6][32 * KP];
    __shared__ float gacc[2][8][16][17];

    int tid = threadIdx.x, bid = blockIdx.x;
    int j0 = bid * 8;
    load_wslice(Whh0h, j0, Wl[0]); load_wslice(Whh0l, j0, Wl[1]);
    load_wslice(Wih1h, j0, Wl[2]); load_wslice(Wih1l, j0, Wl[3]);
    load_wslice(Whh1h, j0, Wl[4]); load_wslice(Whh1l, j0, Wl[5]);

    int bb = (tid & 127) >> 3, jl = tid & 7, j = j0 + jl, lay = tid >> 7;
    float creg = c0p[lay * 4096 + bb * 256 + j];
    float bs[4] = {0.f, 0.f, 0.f, 0.f};
    if (lay) {
#pragma unroll
        for (int q = 0; q < 4; ++q) bs[q] = bih1[q * 256 + j] + bhh1[q * 256 + j];
    }
    f32x4 gnew = {0.f, 0.f, 0.f, 0.f};
    if (!lay) {   // initial prefetch for t=0 (plain load, completes before loop)
        gnew = *(const f32x4*)(gates0 + ((long)bb * 256 + j) * 4);
    }
    {   // init: state slot 0
        float hv = h0p[lay * 4096 + bb * 256 + j];
        short sh, sl; split2s(hv, &sh, &sl);
        int mh = (unsigned short)sh, ml = (unsigned short)sl;
        int nh = __shfl_down(mh, 1), nl = __shfl_down(ml, 1);
        int* dst = (int*)(lay ? H1 : H0);
        if (!(jl & 1)) {
            int idx = bb * 256 + bid * 8 + (jl >> 1);
            st4s(dst + idx, mh | (nh << 16));
            st4s(dst + idx + 4, ml | (nl << 16));
        }
    }

    int lane = tid & 63, w = tid >> 6, cc = lane & 15, g4 = lane >> 4;
    int tw = w & 1, kb = (w >> 1) * 128;
    int abase = cc * 512 + kb * 2 + g4 * 16;       // shorts into a slot
    int wr = (tw * 16 + cc) * KP + kb + (g4 * 8);

    for (int i = 0; i <= SEQ; ++i) {
        bool actL0 = (i < SEQ), actL1 = (i >= 1);
        int par = i & 1;

        // ---- dataflow poll: h0 slot i (L0 h-state AND L1 x) and h1 slot i-1 ----
        short8 f0h[4], f0l[4], f1h[4], f1l[4];
        const short* b0 = H0 + (long)i * SLOT_S + abase;
        const short* b1 = H1 + (long)(i - 1) * SLOT_S + abase;
        int tries = 0;
        while (true) {
#pragma unroll
            for (int ki = 0; ki < 4; ++ki) {
                f0h[ki] = ld16s(b0 + ki * 64);
                f0l[ki] = ld16s(b0 + ki * 64 + 8);
            }
            if (actL1) {
#pragma unroll
                for (int ki = 0; ki < 4; ++ki) {
                    f1h[ki] = ld16s(b1 + ki * 64);
                    f1l[ki] = ld16s(b1 + ki * 64 + 8);
                }
            }
            vmwait();
            unsigned bad = 0;
#pragma unroll
            for (int ki = 0; ki < 4; ++ki) bad |= chk(f0h[ki]) | chk(f0l[ki]);
            if (actL1) {
#pragma unroll
                for (int ki = 0; ki < 4; ++ki) bad |= chk(f1h[ki]) | chk(f1l[ki]);
            }
            if (!__any((int)bad) || ++tries > MAXTRY) break;
        }

        // rotate gates prefetch; issue next step's (plain load, stays in flight
        // across sync_lds since that barrier does NOT drain vmcnt)
        float gpre[4] = {0.f, 0.f, 0.f, 0.f};
        if (!lay) {
#pragma unroll
            for (int q = 0; q < 4; ++q) gpre[q] = gnew[q];
            if (i + 1 < SEQ)
                gnew = *(const f32x4*)(gates0 + ((long)((i + 1) * BB + bb) * 256 + j) * 4);
        }

        f32x4 z = {0.f, 0.f, 0.f, 0.f};
        f32x4 s0 = z, s1 = z;
        if (actL0) {
            f32x4 a1 = z, a2 = z;
#pragma unroll
            for (int ki = 0; ki < 4; ++ki) {
                short8 wh  = *(const short8*)(Wl[0] + wr + ki * 32);
                short8 wl2 = *(const short8*)(Wl[1] + wr + ki * 32);
                a1 = MFMA(f0h[ki], wh, a1);
                a2 = MFMA(f0h[ki], wl2, a2);
                a2 = MFMA(f0l[ki], wh, a2);
            }
            s0 = a1 + a2;
        }
        if (actL1) {
            f32x4 a1 = z, a2 = z;
#pragma unroll
            for (int ki = 0; ki < 4; ++ki) {
                a1 = MFMA(f0h[ki], *(const short8*)(Wl[2] + wr + ki * 32), a1);
                a2 = MFMA(f0h[ki], *(const short8*)(Wl[3] + wr + ki * 32), a2);
                a2 = MFMA(f0l[ki], *(const short8*)(Wl[2] + wr + ki * 32), a2);
                a1 = MFMA(f1h[ki], *(const short8*)(Wl[4] + wr + ki * 32), a1);
                a2 = MFMA(f1h[ki], *(const short8*)(Wl[5] + wr + ki * 32), a2);
                a2 = MFMA(f1l[ki], *(const short8*)(Wl[4] + wr + ki * 32), a2);
            }
            s1 = a1 + a2;
        }
#pragma unroll
        for (int r = 0; r < 4; ++r) {
            gacc[par][w][g4 * 4 + r][cc] = s0[r];
            gacc[par][4 + w][g4 * 4 + r][cc] = s1[r];
        }
        sync_lds();   // LDS-only barrier: stores & gates prefetch stay in flight

        bool act = lay ? actL1 : actL0;
        if (act) {
            int t = lay ? (i - 1) : i;
            float gv[4];
#pragma unroll
            for (int q = 0; q < 4; ++q) {
                int lr = q * 8 + jl, tl = lr >> 4, c = lr & 15;
                gv[q] = lay ? (gacc[par][4 + tl][bb][c] + gacc[par][6 + tl][bb][c] + bs[q])
                            : (gacc[par][tl][bb][c] + gacc[par][2 + tl][bb][c] + gpre[q]);
            }
            float c = sigm(gv[1]) * creg + sigm(gv[0]) * tanh_f(gv[2]);
            creg = c;
            float h = sigm(gv[3]) * tanh_f(c);
            short sh, sl; split2s(h, &sh, &sl);
            int mh = (unsigned short)sh, ml = (unsigned short)sl;
            int nh = __shfl_down(mh, 1), nl = __shfl_down(ml, 1);
            int* dst = (int*)(lay ? (H1 + (long)i * SLOT_S) : (H0 + (long)(i + 1) * SLOT_S));
            if (!(jl & 1)) {
                int idx = bb * 256 + bid * 8 + (jl >> 1);
                st4s(dst + idx, mh | (nh << 16));
                st4s(dst + idx + 4, ml | (nl << 16));
            }
            if (t == SEQ - 1) hfin[lay * 4096 + bb * 256 + j] = h;
        }
    }
}

// ---------------- decoder: dataflow, 2 phases/step, register h-handoff ----------------
__global__ void __launch_bounds__(256, 1) k_dec_coop(
        const short* __restrict__ Wihh, const short* __restrict__ Wihl,
        const short* __restrict__ Whhh, const short* __restrict__ Whhl,
        const float* __restrict__ dbih, const float* __restrict__ dbhh,
        const float* __restrict__ tef, const float* __restrict__ hfin,
        short* __restrict__ H0, short* __restrict__ H1,    // [128][SLOT_S]
        short* __restrict__ TE,                            // [SLOT_S]
        float* __restrict__ preds) {
    __shared__ short Wl[8][32 * KP];
    __shared__ float gacc[2][4][16][17];
    const int WN = GG * EE;

    int tid = threadIdx.x, bid = blockIdx.x;
    int j0 = bid * 8;
    load_wslice(Wihh, j0, Wl[0]);      load_wslice(Wihl, j0, Wl[1]);
    load_wslice(Whhh, j0, Wl[2]);      load_wslice(Whhl, j0, Wl[3]);
    load_wslice(Wihh + WN, j0, Wl[4]); load_wslice(Wihl + WN, j0, Wl[5]);
    load_wslice(Whhh + WN, j0, Wl[6]); load_wslice(Whhl + WN, j0, Wl[7]);

    int bb = (tid & 127) >> 3, jl = tid & 7, j = j0 + jl;
    float c0r = 0.f, c1r = 0.f;
    float bs0[4] = {0,0,0,0}, bs1[4] = {0,0,0,0};
    if (tid < 128) {
        float h0v = hfin[bb * 256 + j], h1v = hfin[4096 + bb * 256 + j];
        c0r = h0v; c1r = h1v;                      // source bug: c := h
        preds[bb * 256 + j] = 0.0f;                // predictions[0] = 0
        int idx = bb * 256 + bid * 8 + (jl >> 1);
        short sh, sl;
        split2s(tef[j], &sh, &sl);
        {
            int mh = (unsigned short)sh, ml = (unsigned short)sl;
            int nh = __shfl_down(mh, 1), nl = __shfl_down(ml, 1);
            if (!(jl & 1)) { st4s((int*)TE + idx, mh | (nh << 16));
                             st4s((int*)TE + idx + 4, ml | (nl << 16)); }
        }
        split2s(h0v, &sh, &sl);
        {
            int mh = (unsigned short)sh, ml = (unsigned short)sl;
            int nh = __shfl_down(mh, 1), nl = __shfl_down(ml, 1);
            if (!(jl & 1)) { st4s((int*)H0 + idx, mh | (nh << 16));
                             st4s((int*)H0 + idx + 4, ml | (nl << 16)); }
        }
        split2s(h1v, &sh, &sl);
        {
            int mh = (unsigned short)sh, ml = (unsigned short)sl;
            int nh = __shfl_down(mh, 1), nl = __shfl_down(ml, 1);
            if (!(jl & 1)) { st4s((int*)H1 + idx, mh | (nh << 16));
                             st4s((int*)H1 + idx + 4, ml | (nl << 16)); }
        }
#pragma unroll
        for (int q = 0; q < 4; ++q) {
            bs0[q] = dbih[q*256+j] + dbhh[q*256+j];
            bs1[q] = dbih[GG + q*256+j] + dbhh[GG + q*256+j];
        }
    }

    int lane = tid & 63, w = tid >> 6, cc = lane & 15, g4 = lane >> 4;
    int tw = w & 1, kb = (w >> 1) * 128;
    int abase = cc * 512 + kb * 2 + g4 * 16;
    int wr = (tw * 16 + cc) * KP + kb + (g4 * 8);

    short8 xAh[4], xAl[4], xBh[4], xBl[4], h1ih[4], h1il[4];

    // preload: xB := H0[0], h1i := H1[0] (dataflow poll)
    {
        const short* p0 = H0 + abase;
        const short* p1 = H1 + abase;
        int tries = 0;
        while (true) {
#pragma unroll
            for (int ki = 0; ki < 4; ++ki) {
                xBh[ki] = ld16s(p0 + ki * 64); xBl[ki] = ld16s(p0 + ki * 64 + 8);
                h1ih[ki] = ld16s(p1 + ki * 64); h1il[ki] = ld16s(p1 + ki * 64 + 8);
            }
            vmwait();
            unsigned bad = 0;
#pragma unroll
            for (int ki = 0; ki < 4; ++ki)
                bad |= chk(xBh[ki]) | chk(xBl[ki]) | chk(h1ih[ki]) | chk(h1il[ki]);
            if (!__any((int)bad) || ++tries > MAXTRY) break;
        }
    }

    for (int t = 0; t < TT - 1; ++t) {
        // ---- phase A: layer 0 : x = (t? H1[t] : TE) polled, h = xB regs ----
        {
            const short* px = (t ? H1 + (long)t * SLOT_S : TE) + abase;
            int tries = 0;
            while (true) {
#pragma unroll
                for (int ki = 0; ki < 4; ++ki) {
                    xAh[ki] = ld16s(px + ki * 64); xAl[ki] = ld16s(px + ki * 64 + 8);
                }
                vmwait();
                unsigned bad = 0;
#pragma unroll
                for (int ki = 0; ki < 4; ++ki) bad |= chk(xAh[ki]) | chk(xAl[ki]);
                if (!__any((int)bad) || ++tries > MAXTRY) break;
            }
            f32x4 a1 = {0.f,0.f,0.f,0.f}, a2 = {0.f,0.f,0.f,0.f};
#pragma unroll
            for (int ki = 0; ki < 4; ++ki) {
                a1 = MFMA(xAh[ki], *(const short8*)(Wl[0] + wr + ki * 32), a1);
                a2 = MFMA(xAh[ki], *(const short8*)(Wl[1] + wr + ki * 32), a2);
                a2 = MFMA(xAl[ki], *(const short8*)(Wl[0] + wr + ki * 32), a2);
                a1 = MFMA(xBh[ki], *(const short8*)(Wl[2] + wr + ki * 32), a1);
                a2 = MFMA(xBh[ki], *(const short8*)(Wl[3] + wr + ki * 32), a2);
                a2 = MFMA(xBl[ki], *(const short8*)(Wl[2] + wr + ki * 32), a2);
            }
            f32x4 accs = a1 + a2;
#pragma unroll
            for (int r = 0; r < 4; ++r) gacc[0][w][g4 * 4 + r][cc] = accs[r];
        }
        sync_lds();
        if (tid < 128) {
            float gv[4];
#pragma unroll
            for (int q = 0; q < 4; ++q) {
                int lr = q * 8 + jl;
                gv[q] = gacc[0][lr >> 4][bb][lr & 15] + gacc[0][2 + (lr >> 4)][bb][lr & 15] + bs0[q];
            }
            float c = sigm(gv[1]) * c0r + sigm(gv[0]) * tanh_f(gv[2]);
            c0r = c;
            float h = sigm(gv[3]) * tanh_f(c);
            short sh, sl; split2s(h, &sh, &sl);
            int mh = (unsigned short)sh, ml = (unsigned short)sl;
            int nh = __shfl_down(mh, 1), nl = __shfl_down(ml, 1);
            if (!(jl & 1)) {
                int idx = bb * 256 + bid * 8 + (jl >> 1);
                int* dst = (int*)(H0 + (long)(t + 1) * SLOT_S);
                st4s(dst + idx, mh | (nh << 16));
                st4s(dst + idx + 4, ml | (nl << 16));
            }
        }
        // ---- phase B: layer 1 : x = H0[t+1] polled, h = (t? xA : h1i) regs ----
        {
            const short* px = H0 + (long)(t + 1) * SLOT_S + abase;
            int tries = 0;
            while (true) {
#pragma unroll
                for (int ki = 0; ki < 4; ++ki) {
                    xBh[ki] = ld16s(px + ki * 64); xBl[ki] = ld16s(px + ki * 64 + 8);
                }
                vmwait();
                unsigned bad = 0;
#pragma unroll
                for (int ki = 0; ki < 4; ++ki) bad |= chk(xBh[ki]) | chk(xBl[ki]);
                if (!__any((int)bad) || ++tries > MAXTRY) break;
            }
            f32x4 a1 = {0.f,0.f,0.f,0.f}, a2 = {0.f,0.f,0.f,0.f};
#pragma unroll
            for (int ki = 0; ki < 4; ++ki) {
                short8 hh = t ? xAh[ki] : h1ih[ki];
                short8 hl = t ? xAl[ki] : h1il[ki];
                a1 = MFMA(xBh[ki], *(const short8*)(Wl[4] + wr + ki * 32), a1);
                a2 = MFMA(xBh[ki], *(const short8*)(Wl[5] + wr + ki * 32), a2);
                a2 = MFMA(xBl[ki], *(const short8*)(Wl[4] + wr + ki * 32), a2);
                a1 = MFMA(hh, *(const short8*)(Wl[6] + wr + ki * 32), a1);
                a2 = MFMA(hh, *(const short8*)(Wl[7] + wr + ki * 32), a2);
                a2 = MFMA(hl, *(const short8*)(Wl[6] + wr + ki * 32), a2);
            }
            f32x4 accs = a1 + a2;
#pragma unroll
            for (int r = 0; r < 4; ++r) gacc[1][w][g4 * 4 + r][cc] = accs[r];
        }
        sync_lds();
        if (tid < 128) {
            float gv[4];
#pragma unroll
            for (int q = 0; q < 4; ++q) {
                int lr = q * 8 + jl;
                gv[q] = gacc[1][lr >> 4][bb][lr & 15] + gacc[1][2 + (lr >> 4)][bb][lr & 15] + bs1[q];
            }
            float c = sigm(gv[1]) * c1r + sigm(gv[0]) * tanh_f(gv[2]);
            c1r = c;
            float h = sigm(gv[3]) * tanh_f(c);
            short sh, sl; split2s(h, &sh, &sl);
            int mh = (unsigned short)sh, ml = (unsigned short)sl;
            int nh = __shfl_down(mh, 1), nl = __shfl_down(ml, 1);
            if (!(jl & 1)) {
                int idx = bb * 256 + bid * 8 + (jl >> 1);
                int* dst = (int*)(H1 + (long)(t + 1) * SLOT_S);
                st4s(dst + idx, mh | (nh << 16));
                st4s(dst + idx + 4, ml | (nl << 16));
            }
            preds[((long)(t + 1) * BB + bb) * HH + j] = h;
        }
    }
}

// ---------------- host launch ----------------
extern "C" void kernel_launch(void* const* d_in, const int* in_sizes, int n_in,
                              void* d_out, int out_size, void* d_ws, size_t ws_size,
                              hipStream_t stream) {
    const int*   src   = (const int*)  d_in[0];
    const float* te    = (const float*)d_in[2];
    const float* h0    = (const float*)d_in[3];
    const float* c0    = (const float*)d_in[4];
    const float* table = (const float*)d_in[5];
    const float* eWih  = (const float*)d_in[6];
    const float* eWhh  = (const float*)d_in[7];
    const float* ebih  = (const float*)d_in[8];
    const float* ebhh  = (const float*)d_in[9];
    const float* dWih  = (const float*)d_in[10];
    const float* dWhh  = (const float*)d_in[11];
    const float* dbih  = (const float*)d_in[12];
    const float* dbhh  = (const float*)d_in[13];
    float* preds = (float*)d_out;

    const int WN = GG * EE;
    const size_t MB = 1u << 20;
    char* ws = (char*)d_ws;
    short* eWih_hi = (short*)(ws + 0 * MB);
    short* eWih_lo = (short*)(ws + 1 * MB);
    short* eWhh_hi = (short*)(ws + 2 * MB);
    short* eWhh_lo = (short*)(ws + 3 * MB);
    short* dWih_hi = (short*)(ws + 4 * MB);
    short* dWih_lo = (short*)(ws + 5 * MB);
    short* dWhh_hi = (short*)(ws + 6 * MB);
    short* dWhh_lo = (short*)(ws + 7 * MB);
    short* Xa_hi   = (short*)(ws + 8 * MB);
    short* Xa_lo   = (short*)(ws + 10 * MB);
    float* hfin    = (float*)(ws + 12 * MB);
    short* slots   = (short*)(ws + 13 * MB);
    short* SLe0 = slots;
    short* SLe1 = SLe0 + (long)257 * SLOT_S;
    short* SLd0 = SLe1 + (long)257 * SLOT_S;
    short* SLd1 = SLd0 + (long)128 * SLOT_S;
    short* SLte = SLd1 + (long)128 * SLOT_S;
    float* gates0 = (float*)(ws + 26 * MB);    // [4096][256][4] transposed

    // sentinel-fill all 771 slots (16KB each)
    k_sent<<<3084, 256, 0, stream>>>((unsigned*)slots);

    // all four weight tensors in one launch
    k_cvt4<<<8192, 256, 0, stream>>>(eWih, eWhh, dWih, dWhh, ws);

    k_embed<<<4096, 256, 0, stream>>>(src, table, (__hip_bfloat16*)Xa_hi, (__hip_bfloat16*)Xa_lo);
    k_gemm_in<<<4096, 256, 0, stream>>>((__hip_bfloat16*)Xa_hi, (__hip_bfloat16*)Xa_lo,
                                        (__hip_bfloat16*)eWih_hi, (__hip_bfloat16*)eWih_lo,
                                        ebih, ebhh, gates0);
    k_enc_coop<<<NWG, 256, 0, stream>>>(gates0, eWhh_hi, eWhh_lo,
                                        eWih_hi + WN, eWih_lo + WN, eWhh_hi + WN, eWhh_lo + WN,
                                        ebih + GG, ebhh + GG, h0, c0,
                                        SLe0, SLe1, hfin);

    k_dec_coop<<<NWG, 256, 0, stream>>>(dWih_hi, dWih_lo, dWhh_hi, dWhh_lo,
                                        dbih, dbhh, te, hfin,
                                        SLd0, SLd1, SLte, preds);
    (void)in_sizes; (void)n_in; (void)out_size; (void)ws_size;
}

// Round 12
// 2118.693 us; speedup vs baseline: 1.1230x; 1.1181x over previous
//
#include <hip/hip_runtime.h>
#include <hip/hip_bf16.h>

typedef __attribute__((ext_vector_type(8))) short short8;
typedef __attribute__((ext_vector_type(4))) float f32x4;

#define SEQ   256   // source length S
#define BB    16    // batch
#define EE    256   // embed dim
#define HH    256   // hidden
#define GG    1024  // 4*H
#define TT    128   // target_size
#define NWG   32    // persistent workgroups
#define KP    264   // LDS row stride in shorts
#define SLOT_S 8192 // shorts per h slot: 16 rows x 32 chunks x 16 (8 hi | 8 lo)
#define SENT  0xFF80FF80u   // packed bf16 [-inf|-inf]: unreachable for finite h
#define MAXTRY (1 << 20)

__device__ __forceinline__ float sigm(float x) { return 1.0f / (1.0f + __expf(-x)); }
__device__ __forceinline__ float tanh_f(float x) {
    float e = __expf(2.0f * x);
    return 1.0f - 2.0f / (e + 1.0f);
}
__device__ __forceinline__ void split2s(float v, short* hi, short* lo) {
    __hip_bfloat16 h = __float2bfloat16(v);
    __hip_bfloat16 l = __float2bfloat16(v - __bfloat162float(h));
    *hi = *(short*)&h; *lo = *(short*)&l;
}
__device__ __forceinline__ f32x4 MFMA(short8 a, short8 b, f32x4 c) {
    return __builtin_amdgcn_mfma_f32_16x16x32_bf16(a, b, c, 0, 0, 0);
}

// ---- LLC-direct accesses (sc0 sc1): bypass L1/L2, served at the coherence point ----
__device__ __forceinline__ short8 ld16s(const short* p) {
    short8 r;
    asm volatile("global_load_dwordx4 %0, %1, off sc0 sc1" : "=v"(r) : "v"(p));
    return r;   // valid only after vmwait()
}
__device__ __forceinline__ int ld4f(const int* p) {   // flag load: load + own wait
    int r;
    asm volatile("global_load_dword %0, %1, off sc0 sc1\n\ts_waitcnt vmcnt(0)"
                 : "=v"(r) : "v"(p) : "memory");
    return r;
}
__device__ __forceinline__ void st4s(int* p, int v) {
    asm volatile("global_store_dword %0, %1, off sc0 sc1" :: "v"(p), "v"(v) : "memory");
}
__device__ __forceinline__ void vmwait() {
    asm volatile("s_waitcnt vmcnt(0)" ::: "memory");
    __builtin_amdgcn_sched_barrier(0);
}
// LDS-only block barrier (no vmcnt drain)
__device__ __forceinline__ void sync_lds() {
    __builtin_amdgcn_sched_barrier(0);
    asm volatile("s_waitcnt lgkmcnt(0)" ::: "memory");
    __builtin_amdgcn_s_barrier();
    __builtin_amdgcn_sched_barrier(0);
}
union U8 { short8 s; unsigned u[4]; };
__device__ __forceinline__ unsigned chk(short8 f) {
    U8 x; x.s = f;
    return (unsigned)((x.u[0] == SENT) | (x.u[1] == SENT) | (x.u[2] == SENT) | (x.u[3] == SENT));
}

// ---------------- utility kernels ----------------
__global__ void k_sent(unsigned* p) {   // fill slot+flag region with sentinel
    long i = ((long)blockIdx.x * 256 + threadIdx.x) * 4;
    p[i] = SENT; p[i + 1] = SENT; p[i + 2] = SENT; p[i + 3] = SENT;
}

__global__ void k_cvt4(const float* __restrict__ s0, const float* __restrict__ s1,
                       const float* __restrict__ s2, const float* __restrict__ s3,
                       char* __restrict__ ws) {
    int g = blockIdx.x >> 11;
    int i = (blockIdx.x & 2047) * 256 + threadIdx.x;
    const float* s = (g == 0) ? s0 : (g == 1) ? s1 : (g == 2) ? s2 : s3;
    __hip_bfloat16* hi = (__hip_bfloat16*)(ws + ((size_t)2 * g) * (1u << 20));
    __hip_bfloat16* lo = (__hip_bfloat16*)(ws + ((size_t)2 * g + 1) * (1u << 20));
    short a, b; split2s(s[i], &a, &b);
    hi[i] = *(__hip_bfloat16*)&a; lo[i] = *(__hip_bfloat16*)&b;
}

__global__ void k_embed(const int* __restrict__ src, const float* __restrict__ tab,
                        __hip_bfloat16* __restrict__ xhi, __hip_bfloat16* __restrict__ xlo) {
    int r = blockIdx.x;
    int j = threadIdx.x;
    long idx = src[r];
    short a, b; split2s(tab[idx * EE + j], &a, &b);
    xhi[(long)r * EE + j] = *(__hip_bfloat16*)&a;
    xlo[(long)r * EE + j] = *(__hip_bfloat16*)&b;
}

// ------------- input-side GEMM: gates0T[row][j][q] = X @ Wih0^T + bih0 + bhh0 -------------
__global__ void __launch_bounds__(256) k_gemm_in(
        const __hip_bfloat16* __restrict__ Xhi, const __hip_bfloat16* __restrict__ Xlo,
        const __hip_bfloat16* __restrict__ Whi, const __hip_bfloat16* __restrict__ Wlo,
        const float* __restrict__ bih, const float* __restrict__ bhh,
        float* __restrict__ gates) {
    int lane = threadIdx.x & 63, w = threadIdx.x >> 6;
    int m0 = (blockIdx.x >> 4) * 16;
    int n0 = ((blockIdx.x & 15) * 4 + w) * 16;
    int cc = lane & 15, g = lane >> 4;
    int koff = g * 8;
    const short* xh = (const short*)Xhi + (long)(m0 + cc) * EE + koff;
    const short* xl = (const short*)Xlo + (long)(m0 + cc) * EE + koff;
    const short* wh = (const short*)Whi + (long)(n0 + cc) * EE + koff;
    const short* wl = (const short*)Wlo + (long)(n0 + cc) * EE + koff;
    f32x4 acc1 = {0.f, 0.f, 0.f, 0.f}, acc2 = {0.f, 0.f, 0.f, 0.f};
#pragma unroll
    for (int k = 0; k < EE; k += 32) {
        short8 ah = *(const short8*)(xh + k), al = *(const short8*)(xl + k);
        short8 bh = *(const short8*)(wh + k), bl = *(const short8*)(wl + k);
        acc1 = MFMA(ah, bh, acc1);
        acc2 = MFMA(ah, bl, acc2);
        acc2 = MFMA(al, bh, acc2);
    }
    f32x4 acc = acc1 + acc2;
    int ncol = n0 + cc;
    float bias = bih[ncol] + bhh[ncol];
    int jj = ncol & 255, qq = ncol >> 8;
    int mrow = m0 + g * 4;
#pragma unroll
    for (int r = 0; r < 4; ++r)
        gates[(long)(mrow + r) * GG + jj * 4 + qq] = acc[r] + bias;   // transposed
}

// ---- gather one 32-row weight slice into LDS ----
__device__ __forceinline__ void load_wslice(const short* __restrict__ Wg, int j0,
                                            short* __restrict__ Wl) {
    int tid = threadIdx.x;
    int lr = tid >> 3;
    int q = lr >> 3, jl = lr & 7;
    const short* src = Wg + (long)(q * 256 + j0 + jl) * 256;
    short* dst = Wl + lr * KP;
#pragma unroll
    for (int s = 0; s < 4; ++s) {
        int c = (tid & 7) * 8 + s * 64;
        *(short8*)(dst + c) = *(const short8*)(src + c);
    }
}

// slot layout: [row 0..15][chunk 0..31][8 hi shorts | 8 lo shorts]
// flags: F[slot][32] ints, SENT = not-ready, 1 = ready (producer block b -> F[slot][b])

// ---------------- encoder: flag-gated dataflow wavefront ----------------
__global__ void __launch_bounds__(256, 1) k_enc_coop(
        const float* __restrict__ gates0,                 // [4096][256][4] transposed
        const short* __restrict__ Whh0h, const short* __restrict__ Whh0l,
        const short* __restrict__ Wih1h, const short* __restrict__ Wih1l,
        const short* __restrict__ Whh1h, const short* __restrict__ Whh1l,
        const float* __restrict__ bih1, const float* __restrict__ bhh1,
        const float* __restrict__ h0p, const float* __restrict__ c0p,
        short* __restrict__ H0, short* __restrict__ H1,    // [257][SLOT_S]
        float* __restrict__ hfin,
        int* __restrict__ FE0, int* __restrict__ FE1) {    // [257][32] flags
    __shared__ short Wl[6][32 * KP];
    __shared__ float gacc[2][8][16][17];

    int tid = threadIdx.x, bid = blockIdx.x;
    int j0 = bid * 8;
    load_wslice(Whh0h, j0, Wl[0]); load_wslice(Whh0l, j0, Wl[1]);
    load_wslice(Wih1h, j0, Wl[2]); load_wslice(Wih1l, j0, Wl[3]);
    load_wslice(Whh1h, j0, Wl[4]); load_wslice(Whh1l, j0, Wl[5]);

    int bb = (tid & 127) >> 3, jl = tid & 7, j = j0 + jl, lay = tid >> 7;
    float creg = c0p[lay * 4096 + bb * 256 + j];
    float bs[4] = {0.f, 0.f, 0.f, 0.f};
    if (lay) {
#pragma unroll
        for (int q = 0; q < 4; ++q) bs[q] = bih1[q * 256 + j] + bhh1[q * 256 + j];
    }
    f32x4 gnew = {0.f, 0.f, 0.f, 0.f};
    if (!lay) {
        gnew = *(const f32x4*)(gates0 + ((long)bb * 256 + j) * 4);
    }
    {   // init: state slot 0
        float hv = h0p[lay * 4096 + bb * 256 + j];
        short sh, sl; split2s(hv, &sh, &sl);
        int mh = (unsigned short)sh, ml = (unsigned short)sl;
        int nh = __shfl_down(mh, 1), nl = __shfl_down(ml, 1);
        int* dst = (int*)(lay ? H1 : H0);
        if (!(jl & 1)) {
            int idx = bb * 256 + bid * 8 + (jl >> 1);
            st4s(dst + idx, mh | (nh << 16));
            st4s(dst + idx + 4, ml | (nl << 16));
        }
    }
    __syncthreads();                    // release: all init stores drained
    if (tid == 0) { st4s(FE0 + bid, 1); st4s(FE1 + bid, 1); }

    int lane = tid & 63, w = tid >> 6, cc = lane & 15, g4 = lane >> 4;
    int tw = w & 1, kb = (w >> 1) * 128;
    int abase = cc * 512 + kb * 2 + g4 * 16;
    int wr = (tw * 16 + cc) * KP + kb + (g4 * 8);

    for (int i = 0; i <= SEQ; ++i) {
        bool actL0 = (i < SEQ), actL1 = (i >= 1);
        int par = i & 1;

        // ---- cheap flag poll: wave 3 (no gates prefetch in flight there) ----
        if (tid >= 192) {
            int ln = tid - 192;
            const int* fp = (ln < 32) ? (FE0 + (long)i * 32 + ln)
                                      : (FE1 + (long)(i - 1) * 32 + (ln - 32));
            bool active = (ln < 32) ? true : actL1;
            int tries = 0;
            while (true) {
                int v = active ? ld4f(fp) : 1;
                if (__all(v != (int)SENT) || ++tries > MAXTRY) break;
            }
        }
        sync_lds();                     // rendezvous: data guaranteed committed

        // ---- single data pass (sentinel-checked, fallback loop kept) ----
        short8 f0h[4], f0l[4], f1h[4], f1l[4];
        const short* b0 = H0 + (long)i * SLOT_S + abase;
        const short* b1 = H1 + (long)(i - 1) * SLOT_S + abase;
        int tries = 0;
        while (true) {
#pragma unroll
            for (int ki = 0; ki < 4; ++ki) {
                f0h[ki] = ld16s(b0 + ki * 64);
                f0l[ki] = ld16s(b0 + ki * 64 + 8);
            }
            if (actL1) {
#pragma unroll
                for (int ki = 0; ki < 4; ++ki) {
                    f1h[ki] = ld16s(b1 + ki * 64);
                    f1l[ki] = ld16s(b1 + ki * 64 + 8);
                }
            }
            vmwait();
            unsigned bad = 0;
#pragma unroll
            for (int ki = 0; ki < 4; ++ki) bad |= chk(f0h[ki]) | chk(f0l[ki]);
            if (actL1) {
#pragma unroll
                for (int ki = 0; ki < 4; ++ki) bad |= chk(f1h[ki]) | chk(f1l[ki]);
            }
            if (!__any((int)bad) || ++tries > MAXTRY) break;
        }

        // rotate gates value (gnew complete: data-pass vmwait drained it)
        float gpre[4] = {0.f, 0.f, 0.f, 0.f};
        if (!lay) {
#pragma unroll
            for (int q = 0; q < 4; ++q) gpre[q] = gnew[q];
        }

        f32x4 z = {0.f, 0.f, 0.f, 0.f};
        f32x4 s0 = z, s1 = z;
        if (actL0) {
            f32x4 a1 = z, a2 = z;
#pragma unroll
            for (int ki = 0; ki < 4; ++ki) {
                short8 wh  = *(const short8*)(Wl[0] + wr + ki * 32);
                short8 wl2 = *(const short8*)(Wl[1] + wr + ki * 32);
                a1 = MFMA(f0h[ki], wh, a1);
                a2 = MFMA(f0h[ki], wl2, a2);
                a2 = MFMA(f0l[ki], wh, a2);
            }
            s0 = a1 + a2;
        }
        if (actL1) {
            f32x4 a1 = z, a2 = z;
#pragma unroll
            for (int ki = 0; ki < 4; ++ki) {
                a1 = MFMA(f0h[ki], *(const short8*)(Wl[2] + wr + ki * 32), a1);
                a2 = MFMA(f0h[ki], *(const short8*)(Wl[3] + wr + ki * 32), a2);
                a2 = MFMA(f0l[ki], *(const short8*)(Wl[2] + wr + ki * 32), a2);
                a1 = MFMA(f1h[ki], *(const short8*)(Wl[4] + wr + ki * 32), a1);
                a2 = MFMA(f1h[ki], *(const short8*)(Wl[5] + wr + ki * 32), a2);
                a2 = MFMA(f1l[ki], *(const short8*)(Wl[4] + wr + ki * 32), a2);
            }
            s1 = a1 + a2;
        }
#pragma unroll
        for (int r = 0; r < 4; ++r) {
            gacc[par][w][g4 * 4 + r][cc] = s0[r];
            gacc[par][4 + w][g4 * 4 + r][cc] = s1[r];
        }
        sync_lds();

        bool act = lay ? actL1 : actL0;
        if (act) {
            int t = lay ? (i - 1) : i;
            float gv[4];
#pragma unroll
            for (int q = 0; q < 4; ++q) {
                int lr = q * 8 + jl, tl = lr >> 4, c = lr & 15;
                gv[q] = lay ? (gacc[par][4 + tl][bb][c] + gacc[par][6 + tl][bb][c] + bs[q])
                            : (gacc[par][tl][bb][c] + gacc[par][2 + tl][bb][c] + gpre[q]);
            }
            float c = sigm(gv[1]) * creg + sigm(gv[0]) * tanh_f(gv[2]);
            creg = c;
            float h = sigm(gv[3]) * tanh_f(c);
            short sh, sl; split2s(h, &sh, &sl);
            int mh = (unsigned short)sh, ml = (unsigned short)sl;
            int nh = __shfl_down(mh, 1), nl = __shfl_down(ml, 1);
            int* dst = (int*)(lay ? (H1 + (long)i * SLOT_S) : (H0 + (long)(i + 1) * SLOT_S));
            if (!(jl & 1)) {
                int idx = bb * 256 + bid * 8 + (jl >> 1);
                st4s(dst + idx, mh | (nh << 16));
                st4s(dst + idx + 4, ml | (nl << 16));
            }
            if (t == SEQ - 1) hfin[lay * 4096 + bb * 256 + j] = h;
        }

        __syncthreads();                // release: all h stores drained
        if (tid == 0) {
            if (actL0) st4s(FE0 + (long)(i + 1) * 32 + bid, 1);
            if (actL1) st4s(FE1 + (long)i * 32 + bid, 1);
        }
        // issue next gates prefetch AFTER the release barrier (never drained by it)
        if (!lay && i + 1 < SEQ)
            gnew = *(const f32x4*)(gates0 + ((long)((i + 1) * BB + bb) * 256 + j) * 4);
    }
}

// ---------------- decoder: flag-gated dataflow, 2 phases/step ----------------
__global__ void __launch_bounds__(256, 1) k_dec_coop(
        const short* __restrict__ Wihh, const short* __restrict__ Wihl,
        const short* __restrict__ Whhh, const short* __restrict__ Whhl,
        const float* __restrict__ dbih, const float* __restrict__ dbhh,
        const float* __restrict__ tef, const float* __restrict__ hfin,
        short* __restrict__ H0, short* __restrict__ H1,    // [128][SLOT_S]
        short* __restrict__ TE,                            // [SLOT_S]
        float* __restrict__ preds,
        int* __restrict__ FD0, int* __restrict__ FD1, int* __restrict__ FT) {
    __shared__ short Wl[8][32 * KP];
    __shared__ float gacc[2][4][16][17];
    const int WN = GG * EE;

    int tid = threadIdx.x, bid = blockIdx.x;
    int j0 = bid * 8;
    load_wslice(Wihh, j0, Wl[0]);      load_wslice(Wihl, j0, Wl[1]);
    load_wslice(Whhh, j0, Wl[2]);      load_wslice(Whhl, j0, Wl[3]);
    load_wslice(Wihh + WN, j0, Wl[4]); load_wslice(Wihl + WN, j0, Wl[5]);
    load_wslice(Whhh + WN, j0, Wl[6]); load_wslice(Whhl + WN, j0, Wl[7]);

    int bb = (tid & 127) >> 3, jl = tid & 7, j = j0 + jl;
    float c0r = 0.f, c1r = 0.f;
    float bs0[4] = {0,0,0,0}, bs1[4] = {0,0,0,0};
    if (tid < 128) {
        float h0v = hfin[bb * 256 + j], h1v = hfin[4096 + bb * 256 + j];
        c0r = h0v; c1r = h1v;                      // source bug: c := h
        preds[bb * 256 + j] = 0.0f;                // predictions[0] = 0
        int idx = bb * 256 + bid * 8 + (jl >> 1);
        short sh, sl;
        split2s(tef[j], &sh, &sl);
        {
            int mh = (unsigned short)sh, ml = (unsigned short)sl;
            int nh = __shfl_down(mh, 1), nl = __shfl_down(ml, 1);
            if (!(jl & 1)) { st4s((int*)TE + idx, mh | (nh << 16));
                             st4s((int*)TE + idx + 4, ml | (nl << 16)); }
        }
        split2s(h0v, &sh, &sl);
        {
            int mh = (unsigned short)sh, ml = (unsigned short)sl;
            int nh = __shfl_down(mh, 1), nl = __shfl_down(ml, 1);
            if (!(jl & 1)) { st4s((int*)H0 + idx, mh | (nh << 16));
                             st4s((int*)H0 + idx + 4, ml | (nl << 16)); }
        }
        split2s(h1v, &sh, &sl);
        {
            int mh = (unsigned short)sh, ml = (unsigned short)sl;
            int nh = __shfl_down(mh, 1), nl = __shfl_down(ml, 1);
            if (!(jl & 1)) { st4s((int*)H1 + idx, mh | (nh << 16));
                             st4s((int*)H1 + idx + 4, ml | (nl << 16)); }
        }
#pragma unroll
        for (int q = 0; q < 4; ++q) {
            bs0[q] = dbih[q*256+j] + dbhh[q*256+j];
            bs1[q] = dbih[GG + q*256+j] + dbhh[GG + q*256+j];
        }
    }
    __syncthreads();                    // release init stores
    if (tid == 0) { st4s(FT + bid, 1); st4s(FD0 + bid, 1); st4s(FD1 + bid, 1); }

    int lane = tid & 63, w = tid >> 6, cc = lane & 15, g4 = lane >> 4;
    int tw = w & 1, kb = (w >> 1) * 128;
    int abase = cc * 512 + kb * 2 + g4 * 16;
    int wr = (tw * 16 + cc) * KP + kb + (g4 * 8);

    short8 xAh[4], xAl[4], xBh[4], xBl[4], h1ih[4], h1il[4];

    // preload: xB := H0[0], h1i := H1[0] (flag-gated)
    {
        if (tid >= 192) {
            int ln = tid - 192;
            const int* fp = (ln < 32) ? (FD0 + ln) : (FD1 + (ln - 32));
            int tries = 0;
            while (true) {
                int v = ld4f(fp);
                if (__all(v != (int)SENT) || ++tries > MAXTRY) break;
            }
        }
        sync_lds();
        const short* p0 = H0 + abase;
        const short* p1 = H1 + abase;
        int tries = 0;
        while (true) {
#pragma unroll
            for (int ki = 0; ki < 4; ++ki) {
                xBh[ki] = ld16s(p0 + ki * 64); xBl[ki] = ld16s(p0 + ki * 64 + 8);
                h1ih[ki] = ld16s(p1 + ki * 64); h1il[ki] = ld16s(p1 + ki * 64 + 8);
            }
            vmwait();
            unsigned bad = 0;
#pragma unroll
            for (int ki = 0; ki < 4; ++ki)
                bad |= chk(xBh[ki]) | chk(xBl[ki]) | chk(h1ih[ki]) | chk(h1il[ki]);
            if (!__any((int)bad) || ++tries > MAXTRY) break;
        }
    }

    for (int t = 0; t < TT - 1; ++t) {
        // ---- phase A: layer 0 : x = (t? H1[t] : TE), h = xB regs ----
        {
            if (tid >= 192) {
                int ln = tid - 192;
                const int* fp = t ? (FD1 + (long)t * 32 + ln) : (FT + ln);
                int tries = 0;
                while (true) {
                    int v = (ln < 32) ? ld4f(fp) : 1;
                    if (__all(v != (int)SENT) || ++tries > MAXTRY) break;
                }
            }
            sync_lds();
            const short* px = (t ? H1 + (long)t * SLOT_S : TE) + abase;
            int tries = 0;
            while (true) {
#pragma unroll
                for (int ki = 0; ki < 4; ++ki) {
                    xAh[ki] = ld16s(px + ki * 64); xAl[ki] = ld16s(px + ki * 64 + 8);
                }
                vmwait();
                unsigned bad = 0;
#pragma unroll
                for (int ki = 0; ki < 4; ++ki) bad |= chk(xAh[ki]) | chk(xAl[ki]);
                if (!__any((int)bad) || ++tries > MAXTRY) break;
            }
            f32x4 a1 = {0.f,0.f,0.f,0.f}, a2 = {0.f,0.f,0.f,0.f};
#pragma unroll
            for (int ki = 0; ki < 4; ++ki) {
                a1 = MFMA(xAh[ki], *(const short8*)(Wl[0] + wr + ki * 32), a1);
                a2 = MFMA(xAh[ki], *(const short8*)(Wl[1] + wr + ki * 32), a2);
                a2 = MFMA(xAl[ki], *(const short8*)(Wl[0] + wr + ki * 32), a2);
                a1 = MFMA(xBh[ki], *(const short8*)(Wl[2] + wr + ki * 32), a1);
                a2 = MFMA(xBh[ki], *(const short8*)(Wl[3] + wr + ki * 32), a2);
                a2 = MFMA(xBl[ki], *(const short8*)(Wl[2] + wr + ki * 32), a2);
            }
            f32x4 accs = a1 + a2;
#pragma unroll
            for (int r = 0; r < 4; ++r) gacc[0][w][g4 * 4 + r][cc] = accs[r];
        }
        sync_lds();
        if (tid < 128) {
            float gv[4];
#pragma unroll
            for (int q = 0; q < 4; ++q) {
                int lr = q * 8 + jl;
                gv[q] = gacc[0][lr >> 4][bb][lr & 15] + gacc[0][2 + (lr >> 4)][bb][lr & 15] + bs0[q];
            }
            float c = sigm(gv[1]) * c0r + sigm(gv[0]) * tanh_f(gv[2]);
            c0r = c;
            float h = sigm(gv[3]) * tanh_f(c);
            short sh, sl; split2s(h, &sh, &sl);
            int mh = (unsigned short)sh, ml = (unsigned short)sl;
            int nh = __shfl_down(mh, 1), nl = __shfl_down(ml, 1);
            if (!(jl & 1)) {
                int idx = bb * 256 + bid * 8 + (jl >> 1);
                int* dst = (int*)(H0 + (long)(t + 1) * SLOT_S);
                st4s(dst + idx, mh | (nh << 16));
                st4s(dst + idx + 4, ml | (nl << 16));
            }
        }
        __syncthreads();                // release H0[t+1]
        if (tid == 0) st4s(FD0 + (long)(t + 1) * 32 + bid, 1);

        // ---- phase B: layer 1 : x = H0[t+1], h = (t? xA : h1i) regs ----
        {
            if (tid >= 192) {
                int ln = tid - 192;
                const int* fp = FD0 + (long)(t + 1) * 32 + ln;
                int tries = 0;
                while (true) {
                    int v = (ln < 32) ? ld4f(fp) : 1;
                    if (__all(v != (int)SENT) || ++tries > MAXTRY) break;
                }
            }
            sync_lds();
            const short* px = H0 + (long)(t + 1) * SLOT_S + abase;
            int tries = 0;
            while (true) {
#pragma unroll
                for (int ki = 0; ki < 4; ++ki) {
                    xBh[ki] = ld16s(px + ki * 64); xBl[ki] = ld16s(px + ki * 64 + 8);
                }
                vmwait();
                unsigned bad = 0;
#pragma unroll
                for (int ki = 0; ki < 4; ++ki) bad |= chk(xBh[ki]) | chk(xBl[ki]);
                if (!__any((int)bad) || ++tries > MAXTRY) break;
            }
            f32x4 a1 = {0.f,0.f,0.f,0.f}, a2 = {0.f,0.f,0.f,0.f};
#pragma unroll
            for (int ki = 0; ki < 4; ++ki) {
                short8 hh = t ? xAh[ki] : h1ih[ki];
                short8 hl = t ? xAl[ki] : h1il[ki];
                a1 = MFMA(xBh[ki], *(const short8*)(Wl[4] + wr + ki * 32), a1);
                a2 = MFMA(xBh[ki], *(const short8*)(Wl[5] + wr + ki * 32), a2);
                a2 = MFMA(xBl[ki], *(const short8*)(Wl[4] + wr + ki * 32), a2);
                a1 = MFMA(hh, *(const short8*)(Wl[6] + wr + ki * 32), a1);
                a2 = MFMA(hh, *(const short8*)(Wl[7] + wr + ki * 32), a2);
                a2 = MFMA(hl, *(const short8*)(Wl[6] + wr + ki * 32), a2);
            }
            f32x4 accs = a1 + a2;
#pragma unroll
            for (int r = 0; r < 4; ++r) gacc[1][w][g4 * 4 + r][cc] = accs[r];
        }
        sync_lds();
        if (tid < 128) {
            float gv[4];
#pragma unroll
            for (int q = 0; q < 4; ++q) {
                int lr = q * 8 + jl;
                gv[q] = gacc[1][lr >> 4][bb][lr & 15] + gacc[1][2 + (lr >> 4)][bb][lr & 15] + bs1[q];
            }
            float c = sigm(gv[1]) * c1r + sigm(gv[0]) * tanh_f(gv[2]);
            c1r = c;
            float h = sigm(gv[3]) * tanh_f(c);
            short sh, sl; split2s(h, &sh, &sl);
            int mh = (unsigned short)sh, ml = (unsigned short)sl;
            int nh = __shfl_down(mh, 1), nl = __shfl_down(ml, 1);
            if (!(jl & 1)) {
                int idx = bb * 256 + bid * 8 + (jl >> 1);
                int* dst = (int*)(H1 + (long)(t + 1) * SLOT_S);
                st4s(dst + idx, mh | (nh << 16));
                st4s(dst + idx + 4, ml | (nl << 16));
            }
            preds[((long)(t + 1) * BB + bb) * HH + j] = h;
        }
        __syncthreads();                // release H1[t+1]
        if (tid == 0) st4s(FD1 + (long)(t + 1) * 32 + bid, 1);
    }
}

// ---------------- host launch ----------------
extern "C" void kernel_launch(void* const* d_in, const int* in_sizes, int n_in,
                              void* d_out, int out_size, void* d_ws, size_t ws_size,
                              hipStream_t stream) {
    const int*   src   = (const int*)  d_in[0];
    const float* te    = (const float*)d_in[2];
    const float* h0    = (const float*)d_in[3];
    const float* c0    = (const float*)d_in[4];
    const float* table = (const float*)d_in[5];
    const float* eWih  = (const float*)d_in[6];
    const float* eWhh  = (const float*)d_in[7];
    const float* ebih  = (const float*)d_in[8];
    const float* ebhh  = (const float*)d_in[9];
    const float* dWih  = (const float*)d_in[10];
    const float* dWhh  = (const float*)d_in[11];
    const float* dbih  = (const float*)d_in[12];
    const float* dbhh  = (const float*)d_in[13];
    float* preds = (float*)d_out;

    const int WN = GG * EE;
    const size_t MB = 1u << 20;
    char* ws = (char*)d_ws;
    short* eWih_hi = (short*)(ws + 0 * MB);
    short* eWih_lo = (short*)(ws + 1 * MB);
    short* eWhh_hi = (short*)(ws + 2 * MB);
    short* eWhh_lo = (short*)(ws + 3 * MB);
    short* dWih_hi = (short*)(ws + 4 * MB);
    short* dWih_lo = (short*)(ws + 5 * MB);
    short* dWhh_hi = (short*)(ws + 6 * MB);
    short* dWhh_lo = (short*)(ws + 7 * MB);
    short* Xa_hi   = (short*)(ws + 8 * MB);
    short* Xa_lo   = (short*)(ws + 10 * MB);
    float* hfin    = (float*)(ws + 12 * MB);
    short* slots   = (short*)(ws + 13 * MB);
    short* SLe0 = slots;
    short* SLe1 = SLe0 + (long)257 * SLOT_S;
    short* SLd0 = SLe1 + (long)257 * SLOT_S;
    short* SLd1 = SLd0 + (long)128 * SLOT_S;
    short* SLte = SLd1 + (long)128 * SLOT_S;
    int*   FL   = (int*)(SLte + (long)1 * SLOT_S);   // flags after slots
    int* FE0 = FL;                 // [257][32]
    int* FE1 = FL + 257 * 32;      // [257][32]
    int* FD0 = FE1 + 257 * 32;     // [128][32]
    int* FD1 = FD0 + 128 * 32;     // [128][32]
    int* FT  = FD1 + 128 * 32;     // [32]
    float* gates0 = (float*)(ws + 26 * MB);    // [4096][256][4] transposed

    // sentinel-fill slots + flags: 771*16384 + 24672*4 = 12,730,752 B -> 3109 blocks
    k_sent<<<3109, 256, 0, stream>>>((unsigned*)slots);

    k_cvt4<<<8192, 256, 0, stream>>>(eWih, eWhh, dWih, dWhh, ws);

    k_embed<<<4096, 256, 0, stream>>>(src, table, (__hip_bfloat16*)Xa_hi, (__hip_bfloat16*)Xa_lo);
    k_gemm_in<<<4096, 256, 0, stream>>>((__hip_bfloat16*)Xa_hi, (__hip_bfloat16*)Xa_lo,
                                        (__hip_bfloat16*)eWih_hi, (__hip_bfloat16*)eWih_lo,
                                        ebih, ebhh, gates0);
    k_enc_coop<<<NWG, 256, 0, stream>>>(gates0, eWhh_hi, eWhh_lo,
                                        eWih_hi + WN, eWih_lo + WN, eWhh_hi + WN, eWhh_lo + WN,
                                        ebih + GG, ebhh + GG, h0, c0,
                                        SLe0, SLe1, hfin, FE0, FE1);

    k_dec_coop<<<NWG, 256, 0, stream>>>(dWih_hi, dWih_lo, dWhh_hi, dWhh_lo,
                                        dbih, dbhh, te, hfin,
                                        SLd0, SLd1, SLte, preds, FD0, FD1, FT);
    (void)in_sizes; (void)n_in; (void)out_size; (void)ws_size;
}